// Round 9
// baseline (133.341 us; speedup 1.0000x reference)
//
#include <hip/hip_runtime.h>

namespace {
constexpr int B = 16, C = 19, H = 512, W = 512;
constexpr int TPB = 256;               // one column per thread
constexpr int HC = 128;                // output rows per block
constexpr int NHC = H / HC;            // 4
constexpr int NWB = W / TPB;           // 2
constexpr int NXCD = 8;
constexpr int TILES = B * NHC * NWB;   // 128 (b,hc,wb) target tiles
constexpr int TPX = TILES / NXCD;      // 16
constexpr int NBLK = TILES * C;        // 2432 = 8*304 (XCD swizzle bijective)
constexpr float SCALE = 1.0f / (float)((long long)B * H * W);
}

// Raw row loads (1 col/thread): 3 X + 3 T coalesced scalars.
struct Raw { float xm, x0, xp; int tm, t0, tp; };
// Separable-Sobel row aggregates: d=x[w+1]-x[w-1]; s=x[w-1]+2x[w]+x[w+1];
// e,u same on one-hot mask. gx=d(-1)+2d(0)+d(+1); gy=s(+1)-s(-1).
struct Agg { float d, s, e, u; };

__global__ void zero_out_kernel(float* out) { *out = 0.0f; }

__global__ __launch_bounds__(TPB) void edge_loss_kernel(
    const float* __restrict__ X,   // [B,C,H,W] f32
    const int*   __restrict__ T,   // [B,H,W] int32 labels
    float* __restrict__ out)
{
    // XCD swizzle: bid%8 -> XCD; the 19 class-blocks of one (b,hc,wb) tile are
    // adjacent on ONE XCD -> its T tile stays L2-resident.
    int i = (int)blockIdx.x;
    const int xcd  = i & (NXCD - 1);
    const int j    = i >> 3;
    const int c    = j % C;
    const int tl   = j / C;
    const int tile = xcd * TPX + tl;
    const int wb   = tile & 1;
    const int hcb  = (tile >> 1) & (NHC - 1);
    const int b    = tile >> 3;
    const int h0   = hcb * HC;

    const int tid = (int)threadIdx.x;
    const int w   = wb * TPB + tid;            // global column 0..511

    // clamped halo columns + border factors (per-thread constants)
    const int   wm = (w > 0)     ? (w - 1) : 0;
    const int   wp = (w < W - 1) ? (w + 1) : (W - 1);
    const float fl = (w > 0)     ? 1.0f : 0.0f;
    const float fr = (w < W - 1) ? 1.0f : 0.0f;

    const float* __restrict__ Xs = X + (size_t)(b * C + c) * (size_t)(H * W);
    const int*   __restrict__ Ts = T + (size_t)b * (size_t)(H * W);

    // wave-uniform row offset (scalarizes to SGPR; SALU adds per row)
    int roff = ((hcb == 0) ? 0 : (h0 - 1)) * W;
    const int step1 = (hcb == 0) ? 0 : W;

    Raw q0, q1, q2;
    Agg g0, g1, g2;
    float acc = 0.0f;

#define ISSUE_AT(Q, RO)                                              \
    {                                                                \
        const float* xrow = Xs + (RO);                               \
        const int*   trow = Ts + (RO);                               \
        (Q).xm = xrow[wm]; (Q).x0 = xrow[w]; (Q).xp = xrow[wp];      \
        (Q).tm = trow[wm]; (Q).t0 = trow[w]; (Q).tp = trow[wp];      \
    }

#define AGG(G, Q)                                                    \
    {                                                                \
        const float xm = (Q).xm * fl;                                \
        const float xp = (Q).xp * fr;                                \
        const float mm = ((Q).tm == c) ? fl  : 0.f;                  \
        const float m0 = ((Q).t0 == c) ? 1.f : 0.f;                  \
        const float mp = ((Q).tp == c) ? fr  : 0.f;                  \
        (G).d = xp - xm;                                             \
        (G).s = fmaf(2.f, (Q).x0, xm + xp);                          \
        (G).e = mp - mm;                                             \
        (G).u = fmaf(2.f, m0, mm + mp);                              \
    }

#define ZAGG(G) { (G).d = (G).s = (G).e = (G).u = 0.f; }

#define COMP(A, Bb, Cc)                                              \
    {                                                                \
        const float gx = fmaf(2.f, (Bb).d, (A).d + (Cc).d);          \
        const float gy = (Cc).s - (A).s;                             \
        const float hx = fmaf(2.f, (Bb).e, (A).e + (Cc).e);          \
        const float hy = (Cc).u - (A).u;                             \
        const float dd = (fabsf(gx) + fabsf(gy))                     \
                       - (fabsf(hx) + fabsf(hy));                    \
        acc = fmaf(dd, dd, acc);                                     \
    }

    // ---- prologue: fill distance-2 pipeline ----
    ISSUE_AT(q0, roff); roff += step1;     // row h0-1 (clamped; row 0 if hc==0)
    ISSUE_AT(q1, roff); roff += W;         // row h0
    AGG(g0, q0);
    if (hcb == 0) ZAGG(g0);                // zero-pad above image
    AGG(g1, q1);
    ISSUE_AT(q1, roff); roff += W;         // row h0+1  -> q1
    ISSUE_AT(q2, roff); roff += W;         // row h0+2  -> q2

    // ---- steady state: step k issues row h0+k+3, aggregates row h0+k+1
    //      (issued 2 steps earlier), outputs row h0+k.  k = 0..122 ----
    for (int t = 0; t < 41; ++t) {
        ISSUE_AT(q0, roff); roff += W; AGG(g2, q1); COMP(g0, g1, g2);
        ISSUE_AT(q1, roff); roff += W; AGG(g0, q2); COMP(g1, g2, g0);
        ISSUE_AT(q2, roff); roff += W; AGG(g1, q0); COMP(g2, g0, g1);
    }
    // k=123: issue row h0+126, agg row h0+124, out row h0+123
    ISSUE_AT(q0, roff); roff += W; AGG(g2, q1); COMP(g0, g1, g2);
    // k=124: issue row h0+127, agg row h0+125, out row h0+124
    ISSUE_AT(q1, roff); roff += W; AGG(g0, q2); COMP(g1, g2, g0);
    // k=125: issue row h0+128 (clamped back for last chunk), agg 126, out 125
    {
        const int ro = (hcb == NHC - 1) ? (roff - W) : roff;
        ISSUE_AT(q2, ro);
        AGG(g1, q0); COMP(g2, g0, g1);
    }
    // k=126: agg row h0+127, out row h0+126
    AGG(g2, q1); COMP(g0, g1, g2);
    // k=127: agg row h0+128 (zero-pad if last chunk), out row h0+127
    AGG(g0, q2);
    if (hcb == NHC - 1) ZAGG(g0);
    COMP(g1, g2, g0);

#undef ISSUE_AT
#undef AGG
#undef ZAGG
#undef COMP

    // ---- reduce: wave shuffle -> LDS (4 waves) -> one atomic per block ----
    #pragma unroll
    for (int off = 32; off > 0; off >>= 1)
        acc += __shfl_down(acc, off, 64);

    __shared__ float wsum[TPB / 64];
    const int lane = tid & 63;
    const int wid  = tid >> 6;
    if (lane == 0) wsum[wid] = acc;
    __syncthreads();
    if (tid == 0)
        atomicAdd(out, (wsum[0] + wsum[1] + wsum[2] + wsum[3]) * SCALE);
}

extern "C" void kernel_launch(void* const* d_in, const int* in_sizes, int n_in,
                              void* d_out, int out_size, void* d_ws, size_t ws_size,
                              hipStream_t stream) {
    (void)in_sizes; (void)n_in; (void)d_ws; (void)ws_size; (void)out_size;
    const float* X = (const float*)d_in[0];
    const int*   T = (const int*)d_in[1];
    float* out = (float*)d_out;

    zero_out_kernel<<<1, 1, 0, stream>>>(out);
    edge_loss_kernel<<<NBLK, TPB, 0, stream>>>(X, T, out);
}